// Round 5
// baseline (955.095 us; speedup 1.0000x reference)
//
#include <hip/hip_runtime.h>

// ---------------------------------------------------------------------------
// Fused attention block, bf16 MFMA pipeline.
// B=4, L=2048, HID=2048, H=16, DH=128, QKV=6144.
// R10 = R9 resubmitted verbatim (R9 bench died to container infra, not the
// kernel: barrier balance, vmcnt drain math, LDS bounds all re-audited).
// R9: software-pipelined GEMM core — frag ds_reads issued ONE PHASE AHEAD
// (double-buffered af[2] / bfA,bfB register sets), so the LDS-read burst
// executes under the previous phase's MFMA window instead of alternating
// with it (R8 cycle model: 1400 cyc/phase = 620 MFMA + ~600 exposed LDS +
// bars; prediction ~900 cyc/phase). Next-tile q0+B frags issued at p3 after
// VM6+bar (buffer globally valid there). Barriers/staging unchanged (R6-
// proven). fa: LPT dispatch — heavy diagonal blocks (qc=7) launch first.
// ---------------------------------------------------------------------------

typedef __attribute__((ext_vector_type(8))) short bf16x8;   // 8 bf16 = 4 VGPRs
typedef __attribute__((ext_vector_type(4))) float f32x4;
typedef __attribute__((ext_vector_type(4))) unsigned short us4;

#if __has_builtin(__builtin_amdgcn_exp2f)
#define EXP2(x) __builtin_amdgcn_exp2f(x)
#else
#define EXP2(x) exp2f(x)
#endif

__device__ __forceinline__ unsigned short f2bf(float f) {
    unsigned int x = __float_as_uint(f);
    unsigned int r = x + 0x7fffu + ((x >> 16) & 1u);   // RN-even
    return (unsigned short)(r >> 16);
}
__device__ __forceinline__ unsigned short f2bf_fast(float f) {   // round-half-up
    return (unsigned short)((__float_as_uint(f) + 0x8000u) >> 16);
}
__device__ __forceinline__ float bf2f(unsigned short u) {
    return __uint_as_float(((unsigned int)u) << 16);
}

// async global->LDS, 16 B per lane; LDS dest = wave-uniform base + lane*16
__device__ __forceinline__ void gll16(const unsigned short* g, unsigned short* l) {
    __builtin_amdgcn_global_load_lds(
        (const __attribute__((address_space(1))) unsigned int*)g,
        (__attribute__((address_space(3))) unsigned int*)l, 16, 0, 0);
}

// raw barrier with compiler memory fence (no vmcnt(0) drain like __syncthreads)
__device__ __forceinline__ void barx() {
    asm volatile("" ::: "memory");
    __builtin_amdgcn_s_barrier();
    asm volatile("" ::: "memory");
}
#define LGKM0() asm volatile("s_waitcnt lgkmcnt(0)" ::: "memory")
#define VM6()   asm volatile("s_waitcnt vmcnt(6)" ::: "memory")
#define VM4()   asm volatile("s_waitcnt vmcnt(4)" ::: "memory")
#define VM0()   asm volatile("s_waitcnt vmcnt(0)" ::: "memory")

// ---------------------------------------------------------------------------
// elementwise fp32 -> bf16 (vectorized float4 -> ushort4)
// ---------------------------------------------------------------------------
__global__ __launch_bounds__(256) void cvt_bf16(const float* __restrict__ in,
                                                unsigned short* __restrict__ out) {
    int i = blockIdx.x * 256 + threadIdx.x;       // over n/4
    float4 v = ((const float4*)in)[i];
    us4 r;
    r[0] = f2bf(v.x); r[1] = f2bf(v.y); r[2] = f2bf(v.z); r[3] = f2bf(v.w);
    ((us4*)out)[i] = r;
}

// ---------------------------------------------------------------------------
// fp32 (R x C) -> bf16 transposed (C x R).  block (32,8), 32x32 LDS tile.
// ---------------------------------------------------------------------------
__global__ __launch_bounds__(256) void transpose_cvt(const float* __restrict__ in,
                                                     unsigned short* __restrict__ out,
                                                     int R, int C) {
    __shared__ float t[32][33];
    int c0 = blockIdx.x * 32, r0 = blockIdx.y * 32;
    int tx = threadIdx.x, ty = threadIdx.y;
#pragma unroll
    for (int i = 0; i < 4; i++)
        t[ty + i * 8][tx] = in[(size_t)(r0 + ty + i * 8) * C + c0 + tx];
    __syncthreads();
#pragma unroll
    for (int i = 0; i < 4; i++)
        out[(size_t)(c0 + ty + i * 8) * R + r0 + tx] = f2bf(t[tx][ty + i * 8]);
}

// ---------------------------------------------------------------------------
// 256x256 software-pipelined 8-phase GEMM core.
// C[256m x 256n] += A(M,K) * Bt(N,K)^T, bf16, BK=64. 512 thr = 8 waves
// (wm=w>>2, wn=w&3); wave output 128x64 = acc[8][4] 16x16x32 frags.
// LDS: sm[2 buf][2 mat][2 half][128*64] = 128 KiB, chunk-XOR swizzle (row&7).
// Schedule per K-tile t (phase q: bar; lgkm0; ISSUE READS FOR q+1;
// MFMA q; bar) — frag reads ride under the MFMA window of the prior phase:
//   p0: stage (t+1)A1 | bar lgkm0 | rd A(q1)->af[1]      | MFMA q0 (af[0])
//   p1: stage (t+2)B0 | bar lgkm0 | rd A(q2)->af[0]      | MFMA q1 (af[1])
//   p2: stage (t+2)B1 | bar lgkm0 | rd A(q3)->af[1]      | MFMA q2 (af[0])
//   p3: stage (t+2)A0, VM6 | bar lgkm0 | rd next-tile B->Bn, A(q0)->af[0]
//                                                        | MFMA q3 (af[1])
// Next-tile reads at p3 are valid: VM6 + barrier => all waves' (t+1) loads
// landed (6 youngest outstanding = (t+2)B0/B1/A0 only). B-frag double
// buffer alternates per tile (bfA/bfB, 2x unrolled tile loop keeps all
// frag indices compile-time — no scratch).
// ---------------------------------------------------------------------------
__device__ __forceinline__ void gemm256_core(const unsigned short* __restrict__ A,
                                             const unsigned short* __restrict__ Bt,
                                             int K, int rowA0, int colB0,
                                             unsigned short* sm,
                                             f32x4 acc[8][4]) {
    const int tid = threadIdx.x;
    const int w = tid >> 6, lane = tid & 63;
    const int quad = lane >> 4, l15 = lane & 15;
    const int wm = w >> 2, wn = w & 3;
    const int lr = lane >> 3;                 // row within the 8-row gll stripe
    const int lc = ((lane & 7) ^ lr) * 8;     // pre-swizzled source col within 64
    const int NT = K >> 6;

    const unsigned short* pA = A  + (size_t)(rowA0 + w * 16 + lr) * K + lc;
    const unsigned short* pB = Bt + (size_t)(colB0 + w * 16 + lr) * K + lc;
    unsigned short* lw = sm + w * 16 * 64;    // wave's stripe within any slab

    bf16x8 bfA[4][2], bfB[4][2];              // B frags, per-tile alternating
    bf16x8 af[2][2][2];                       // A frags [parity][mi][kk]

#define STAGE(tt, isB, h)                                                       \
    do {                                                                        \
        const unsigned short* gp_ = ((isB) ? pB : pA) +                         \
            (size_t)(h) * 128 * K + (size_t)(tt) * 64;                          \
        unsigned short* lp_ = lw + (((tt) & 1) * 4 + (isB) * 2 + (h)) * 8192;   \
        gll16(gp_, lp_);                                                        \
        gll16(gp_ + (size_t)8 * K, lp_ + 8 * 64);                               \
    } while (0)

#define RD_A(par, Asl_, qq)                                                     \
    _Pragma("unroll")                                                           \
    for (int mi = 0; mi < 2; ++mi)                                              \
    _Pragma("unroll")                                                           \
    for (int kk = 0; kk < 2; ++kk) {                                            \
        int r = (qq) * 32 + mi * 16 + l15;                                      \
        af[par][mi][kk] = *(const bf16x8*)&(Asl_)[r * 64 +                      \
            (((kk * 4 + quad) ^ (r & 7)) * 8)];                                 \
    }

#define RD_B(dstB, Bsl_)                                                        \
    _Pragma("unroll")                                                           \
    for (int nj = 0; nj < 4; ++nj)                                              \
    _Pragma("unroll")                                                           \
    for (int kk = 0; kk < 2; ++kk) {                                            \
        int r = (wn & 1) * 64 + nj * 16 + l15;                                  \
        dstB[nj][kk] = *(const bf16x8*)&(Bsl_)[r * 64 +                         \
            (((kk * 4 + quad) ^ (r & 7)) * 8)];                                 \
    }

#define MM(qpar, Bu, qq)                                                        \
    __builtin_amdgcn_s_setprio(1);                                              \
    _Pragma("unroll")                                                           \
    for (int mi = 0; mi < 2; ++mi)                                              \
    _Pragma("unroll")                                                           \
    for (int nj = 0; nj < 4; ++nj)                                              \
    _Pragma("unroll")                                                           \
    for (int kk = 0; kk < 2; ++kk)                                              \
        acc[(qq) * 2 + mi][nj] = __builtin_amdgcn_mfma_f32_16x16x32_bf16(       \
            af[qpar][mi][kk], Bu[nj][kk], acc[(qq) * 2 + mi][nj], 0, 0, 0);     \
    __builtin_amdgcn_s_setprio(0);

#define TILE(t, Bu, Bn)                                                         \
    {                                                                           \
        const unsigned short* Asl = sm + (((t) & 1) * 4 + wm) * 8192;           \
        /* p0 */                                                                \
        if ((t) + 1 < NT) STAGE((t) + 1, 0, 1);                                 \
        barx(); LGKM0();                                                        \
        RD_A(1, Asl, 1);                                                        \
        MM(0, Bu, 0);                                                           \
        barx();                                                                 \
        /* p1 */                                                                \
        if ((t) + 2 < NT) STAGE((t) + 2, 1, 0);                                 \
        barx(); LGKM0();                                                        \
        RD_A(0, Asl, 2);                                                        \
        MM(1, Bu, 1);                                                           \
        barx();                                                                 \
        /* p2 */                                                                \
        if ((t) + 2 < NT) STAGE((t) + 2, 1, 1);                                 \
        barx(); LGKM0();                                                        \
        RD_A(1, Asl, 3);                                                        \
        MM(0, Bu, 2);                                                           \
        barx();                                                                 \
        /* p3 */                                                                \
        if ((t) + 2 < NT)      { STAGE((t) + 2, 0, 0); VM6(); }                 \
        else if ((t) + 1 < NT) { VM0(); }                                       \
        barx(); LGKM0();                                                        \
        if ((t) + 1 < NT) {                                                     \
            const unsigned short* Asn = sm + ((((t) + 1) & 1) * 4 + wm) * 8192; \
            const unsigned short* Bsn = sm + ((((t) + 1) & 1) * 4 + 2 +         \
                                              (wn >> 1)) * 8192;                \
            RD_B(Bn, Bsn);                                                      \
            RD_A(0, Asn, 0);                                                    \
        }                                                                       \
        MM(1, Bu, 3);                                                           \
        barx();                                                                 \
    }

    // prologue: tile0 [B0,B1,A0,A1], tile1 [B0,B1,A0]; 14 loads/wave in
    // flight, VM6 -> own tile0 slabs landed; bar -> tile0 valid for all.
    STAGE(0, 1, 0); STAGE(0, 1, 1); STAGE(0, 0, 0); STAGE(0, 0, 1);
    STAGE(1, 1, 0); STAGE(1, 1, 1); STAGE(1, 0, 0);
    VM6();
    barx();
    {
        const unsigned short* Asl0 = sm + wm * 8192;
        const unsigned short* Bsl0 = sm + (2 + (wn >> 1)) * 8192;
        RD_B(bfA, Bsl0);
        RD_A(0, Asl0, 0);
    }
    for (int tt = 0; tt < NT; tt += 2) {
        TILE(tt, bfA, bfB);
        TILE(tt + 1, bfB, bfA);
    }
#undef TILE
#undef MM
#undef RD_B
#undef RD_A
#undef STAGE
}

// ---------------------------------------------------------------------------
// GEMM1: proj = Xb @ Wqkvg.  256-col tile = 2 heads of one section.
// Epilogue: q/k scatter -> (b,h,l,d); V written TRANSPOSED -> Vt (b,h,d,l)
// via 128 KiB LDS reuse (fused transpose_v); gate -> sigmoid.
// Mapping (R6-proven): per-XCD 4 by-rows x all 32 bx — A-slab L2-resident,
// B streamed via LLC.
// ---------------------------------------------------------------------------
__global__ __launch_bounds__(512) void gemm_qkvg(const unsigned short* __restrict__ A,
                                                 const unsigned short* __restrict__ Bt,
                                                 unsigned short* __restrict__ Qb,
                                                 unsigned short* __restrict__ Kb,
                                                 unsigned short* __restrict__ Vt,
                                                 unsigned short* __restrict__ Gb) {
    __shared__ unsigned short sm[8 * 8192];    // 128 KiB
    f32x4 acc[8][4];
    f32x4 z = {0.f, 0.f, 0.f, 0.f};
#pragma unroll
    for (int i = 0; i < 8; i++)
#pragma unroll
        for (int j = 0; j < 4; j++) acc[i][j] = z;

    // XCD-chunked bijective swizzle (1024 wgs, 1024 % 8 == 0)
    const int g = blockIdx.y * 32 + blockIdx.x;
    const int gs = (g & 7) * 128 + (g >> 3);
    const int bx = gs & 31, by = gs >> 5;
    const int rowA0 = by * 256, colB0 = bx * 256;
    gemm256_core(A, Bt, 2048, rowA0, colB0, sm, acc);

    const int tid = threadIdx.x, w = tid >> 6, lane = tid & 63;
    const int quad = lane >> 4, l15 = lane & 15;
    const int wm = w >> 2, wn = w & 3;
    const int sec = colB0 >> 11;              // 0=q 1=k 2=v 3=gate
    const int hbase = (colB0 & 2047) >> 7;    // even head base within section

    if (sec == 2) {
        // V: acc -> LDS as two (d, l) 128x256 head-tiles, 16B-chunk swizzled
        // (chunk ^= d&31); core's final barrier means all LDS reads are done.
#pragma unroll
        for (int mi = 0; mi < 8; ++mi)
#pragma unroll
            for (int nj = 0; nj < 4; ++nj)
#pragma unroll
                for (int i = 0; i < 4; ++i) {
                    int ll = wm * 128 + mi * 16 + quad * 4 + i;   // l in tile
                    int c  = wn * 64 + nj * 16 + l15;             // 0..255
                    int hh = c >> 7, d = c & 127;
                    sm[hh * 32768 + d * 256 + (((ll >> 3) ^ (d & 31)) * 8) + (ll & 7)] =
                        f2bf(acc[mi][nj][i]);
                }
        __syncthreads();
        const int b_ = rowA0 >> 11, l0 = rowA0 & 2047;
        const int d = tid >> 2, part = tid & 3;    // d row, 64-col quarter
#pragma unroll
        for (int hh = 0; hh < 2; ++hh) {
            unsigned short* drow = Vt +
                ((size_t)(b_ * 16 + hbase + hh) * 128 + d) * 2048 + l0 + part * 64;
#pragma unroll
            for (int j = 0; j < 8; ++j) {
                int chunk = part * 8 + j;
                *(bf16x8*)(drow + j * 8) =
                    *(const bf16x8*)&sm[hh * 32768 + d * 256 + ((chunk ^ (d & 31)) * 8)];
            }
        }
    } else if (sec == 3) {
#pragma unroll
        for (int mi = 0; mi < 8; ++mi)
#pragma unroll
            for (int nj = 0; nj < 4; ++nj)
#pragma unroll
                for (int i = 0; i < 4; ++i) {
                    int rowg = rowA0 + wm * 128 + mi * 16 + quad * 4 + i;  // b*L+l
                    int c = wn * 64 + nj * 16 + l15;
                    int h = hbase + (c >> 7), d = c & 127;
                    float gv = 1.f / (1.f + __expf(-acc[mi][nj][i]));
                    Gb[((size_t)rowg << 11) + h * 128 + d] = f2bf(gv);
                }
    } else {
        unsigned short* dst = (sec == 0) ? Qb : Kb;
#pragma unroll
        for (int mi = 0; mi < 8; ++mi)
#pragma unroll
            for (int nj = 0; nj < 4; ++nj)
#pragma unroll
                for (int i = 0; i < 4; ++i) {
                    int rowg = rowA0 + wm * 128 + mi * 16 + quad * 4 + i;
                    int c = wn * 64 + nj * 16 + l15;
                    int h = hbase + (c >> 7), d = c & 127;
                    int b_ = rowg >> 11, l_ = rowg & 2047;
                    dst[(((size_t)(b_ * 16 + h) * 2048 + l_) << 7) + d] =
                        f2bf(acc[mi][nj][i]);
                }
    }
}

// ---------------------------------------------------------------------------
// GEMM2: out = OG @ Wout  (fp32 epilogue straight to d_out)
// ---------------------------------------------------------------------------
__global__ __launch_bounds__(512) void gemm_out(const unsigned short* __restrict__ A,
                                                const unsigned short* __restrict__ Bt,
                                                float* __restrict__ C) {
    __shared__ unsigned short sm[8 * 8192];    // 128 KiB
    f32x4 acc[8][4];
    f32x4 z = {0.f, 0.f, 0.f, 0.f};
#pragma unroll
    for (int i = 0; i < 8; i++)
#pragma unroll
        for (int j = 0; j < 4; j++) acc[i][j] = z;

    const int g = blockIdx.y * 8 + blockIdx.x;      // 256 wgs, 256 % 8 == 0
    const int gs = (g & 7) * 32 + (g >> 3);
    const int bx = gs & 7, by = gs >> 3;
    const int rowA0 = by * 256, colB0 = bx * 256;
    gemm256_core(A, Bt, 2048, rowA0, colB0, sm, acc);

    const int tid = threadIdx.x, w = tid >> 6, lane = tid & 63;
    const int quad = lane >> 4, l15 = lane & 15;
    const int wm = w >> 2, wn = w & 3;
#pragma unroll
    for (int mi = 0; mi < 8; ++mi)
#pragma unroll
        for (int nj = 0; nj < 4; ++nj)
#pragma unroll
            for (int i = 0; i < 4; ++i) {
                int rowg = rowA0 + wm * 128 + mi * 16 + quad * 4 + i;
                int col = colB0 + wn * 64 + nj * 16 + l15;
                C[(size_t)rowg * 2048 + col] = acc[mi][nj][i];
            }
}

// ---------------------------------------------------------------------------
// RMSNorm + RoPE in place on Q and K (each (64, 2048, 128) bf16), one launch.
// Vectorized — 16 lanes per row, bf16x8 (16B) loads/stores. Lane l16 owns
// elements [sub*64 + l8*8, +8); SS reduced over the 16-lane group; rotate-
// half partner via shfl_xor(8,16). 4 rows/wave, 16 rows/block.
// ---------------------------------------------------------------------------
__global__ __launch_bounds__(256) void rmsnorm_rope(unsigned short* __restrict__ Qp,
                                                    unsigned short* __restrict__ Kp) {
    unsigned short* X = blockIdx.y ? Kp : Qp;
    const int tid = threadIdx.x;
    const int wv = tid >> 6, lane = tid & 63;
    const int rgrp = lane >> 4;                 // row within wave: 0..3
    const int l16 = lane & 15;
    const int sub = l16 >> 3, l8 = l16 & 7;     // half, 8-elem chunk
    const int row = blockIdx.x * 16 + wv * 4 + rgrp;
    unsigned short* p = X + (size_t)row * 128 + sub * 64 + l8 * 8;
    const int pos = row & 2047;                 // sequence position

    bf16x8 v = *(const bf16x8*)p;
    float x[8];
    float ss = 0.f;
#pragma unroll
    for (int j = 0; j < 8; j++) {
        x[j] = bf2f((unsigned short)v[j]);
        ss += x[j] * x[j];
    }
#pragma unroll
    for (int off = 8; off >= 1; off >>= 1) ss += __shfl_xor(ss, off, 16);
    const float r = rsqrtf(ss * (1.f / 128.f) + 1e-5f);

    float xs[8], xp[8];
#pragma unroll
    for (int j = 0; j < 8; j++) xs[j] = x[j] * r;
#pragma unroll
    for (int j = 0; j < 8; j++) xp[j] = __shfl_xor(xs[j], 8, 16);  // other half

    const float sgn = sub ? 1.f : -1.f;     // out = xs*cos + xp*(sub? sin:-sin)
    bf16x8 o;
#pragma unroll
    for (int j = 0; j < 8; j++) {
        int k = l8 * 8 + j;                  // frequency index 0..63
        float inv = exp2f(-(float)k * (13.287712379549449f / 64.f));
        float ang = (float)pos * inv;
        float sn, cs;
        sincosf(ang, &sn, &cs);
        o[j] = (short)f2bf(xs[j] * cs + xp[j] * (sgn * sn));
    }
    *(bf16x8*)p = o;
}

// ---------------------------------------------------------------------------
// Flash attention (causal) + gate fusion, no-max softmax.
// grid 512 blocks, 512 threads = 8 waves; q-tile 256 (wave w owns q rows
// [w*32, w*32+32)); KV tile 64, PV in two 32-kv halves so Ps is 16 KB.
// K/V double-buffered (LDS 80 KB), tile j+1 prefetched during tile j
// compute, counted vmcnt(4); setprio around MFMA clusters (T5).
// LPT dispatch — qc reversed so heavy (qc=7, 32-tile) blocks launch
// first and light ones backfill: better tail makespan.
// Block mapping groups all 8 q-chunks of a head on one XCD.
// P is wave-local: no barrier between P write and PV read.
// ---------------------------------------------------------------------------
__global__ __launch_bounds__(512) void fa_kernel(const unsigned short* __restrict__ Q,
                                                 const unsigned short* __restrict__ K,
                                                 const unsigned short* __restrict__ Vt,
                                                 const unsigned short* __restrict__ G,
                                                 unsigned short* __restrict__ Og) {
    __shared__ unsigned short Ks[2][64 * 128];  // (kv, d) double-buffered
    __shared__ unsigned short Vs[2][128 * 64];  // (d, kv) double-buffered
    __shared__ unsigned short Ps[256 * 32];     // (q, kv-half) wave-local slabs
    const int g = blockIdx.x;
    const int bh = (g & 7) | ((g >> 6) << 3);   // all qc of a head share g%8
    const int qc = 7 - ((g >> 3) & 7);          // LPT: heavy chunks first
    const int tid = threadIdx.x, w = tid >> 6, lane = tid & 63;
    const int quad = lane >> 4, l15 = lane & 15;
    const int sw = l15 & 7;
    const int qrow0 = qc * 256 + w * 32;        // global q row base for this wave
    const float CS = 0.12751740395609812f;      // (1/sqrt(128)) * log2(e)

    // Q fragments (A-operand layout), loaded once
    bf16x8 qf[2][4];
#pragma unroll
    for (int mi = 0; mi < 2; mi++)
#pragma unroll
        for (int kt = 0; kt < 4; kt++)
            qf[mi][kt] = *(const bf16x8*)(Q + ((size_t)bh * 2048 + qrow0 + mi * 16 + l15) * 128
                                             + kt * 32 + quad * 8);

    f32x4 o[2][8];
    f32x4 z = {0.f, 0.f, 0.f, 0.f};
#pragma unroll
    for (int mi = 0; mi < 2; mi++)
#pragma unroll
        for (int nj = 0; nj < 8; nj++) o[mi][nj] = z;
    float rowsum[2][4];
#pragma unroll
    for (int mi = 0; mi < 2; mi++)
#pragma unroll
        for (int i = 0; i < 4; i++) rowsum[mi][i] = 0.f;

    const unsigned short* Kbase = K + (size_t)bh * 2048 * 128;
    const unsigned short* Vtb   = Vt + (size_t)bh * 128 * 2048;

    // staging lane decomposition (4 gll16 per wave per tile)
    const int krow = lane >> 4, kc = lane & 15;   // K: 4 rows x 16 chunks
    const int vrow = lane >> 3, vc = lane & 7;    // V: 8 rows x 8 chunks

#define STAGE_KV(jj, buf)                                                        \
    do {                                                                         \
        _Pragma("unroll")                                                        \
        for (int i_ = 0; i_ < 2; i_++) {                                         \
            int r0_ = w * 8 + i_ * 4;                                            \
            int row_ = r0_ + krow;                                               \
            int cs_ = (kc & 8) | ((kc & 7) ^ (row_ & 7));                        \
            gll16(Kbase + (size_t)((jj) * 64 + row_) * 128 + cs_ * 8,            \
                  &Ks[buf][r0_ * 128]);                                          \
        }                                                                        \
        _Pragma("unroll")                                                        \
        for (int i_ = 0; i_ < 2; i_++) {                                         \
            int r0_ = w * 16 + i_ * 8;                                           \
            int row_ = r0_ + vrow;                                               \
            gll16(Vtb + (size_t)row_ * 2048 + (jj) * 64 + ((vc ^ (row_ & 7)) * 8), \
                  &Vs[buf][r0_ * 64]);                                           \
        }                                                                        \
    } while (0)

    // Ps a-frag read offsets (row-dependent swizzle key = (row>>1)&3)
    const int pr0 = w * 32 + l15, pr1 = pr0 + 16;
    const int pk0 = (pr0 >> 1) & 3, pk1 = (pr1 >> 1) & 3;

    const int NJ = 4 * (qc + 1);    // kv tiles of 64

    STAGE_KV(0, 0);                 // prologue: tile 0 in flight

    for (int j = 0; j < NJ; j++) {
        const int cur = j & 1;
        // prefetch tile j+1 into the other buffer; its 4 loads ride across
        // this tile's compute. vmcnt(4) waits only for tile j's 4 loads.
        if (j + 1 < NJ) { STAGE_KV(j + 1, cur ^ 1); VM4(); }
        else            { VM0(); }
        barx();   // tile j staged + all waves' prior-tile reads done

        if (j * 64 < qrow0 + 32) {
            // --- S = Q K^T (raw logits) ---
            f32x4 s[2][4];
#pragma unroll
            for (int mi = 0; mi < 2; mi++)
#pragma unroll
                for (int nj = 0; nj < 4; nj++) s[mi][nj] = z;
            __builtin_amdgcn_s_setprio(1);
#pragma unroll
            for (int kt = 0; kt < 4; kt++)
#pragma unroll
                for (int nj = 0; nj < 4; nj++) {
                    bf16x8 bfr = *(const bf16x8*)&Ks[cur][(nj * 16 + l15) * 128 +
                                                         (((kt * 4 + quad) ^ sw) * 8)];
                    s[0][nj] = __builtin_amdgcn_mfma_f32_16x16x32_bf16(qf[0][kt], bfr, s[0][nj], 0, 0, 0);
                    s[1][nj] = __builtin_amdgcn_mfma_f32_16x16x32_bf16(qf[1][kt], bfr, s[1][nj], 0, 0, 0);
                }
            __builtin_amdgcn_s_setprio(0);

            // --- two 32-kv halves: exp + P write + PV MFMA (Ps wave-local) ---
            const bool diag = (j * 64 + 63 > qrow0);   // any masking in this tile?
#pragma unroll
            for (int hh = 0; hh < 2; hh++) {
#pragma unroll
                for (int mi = 0; mi < 2; mi++)
#pragma unroll
                    for (int njh = 0; njh < 2; njh++) {
                        const int nj = hh * 2 + njh;
#pragma unroll
                        for (int i = 0; i < 4; i++) {
                            float pp = EXP2(s[mi][nj][i] * CS);
                            int row_l = mi * 16 + quad * 4 + i;      // 0..31 in slab
                            if (diag) {
                                int col_g = j * 64 + nj * 16 + l15;
                                if (col_g > qrow0 + row_l) pp = 0.f;
                            }
                            rowsum[mi][i] += pp;
                            int row = w * 32 + row_l;
                            int kv = njh * 16 + l15;                 // 0..31
                            Ps[row * 32 + ((((kv >> 3) ^ ((row >> 1) & 3)) * 8)) + (kv & 7)] =
                                f2bf_fast(pp);
                        }
                    }
                // PV for this half (K=32 -> one MFMA pair per o-column)
                bf16x8 a0 = *(const bf16x8*)&Ps[pr0 * 32 + ((quad ^ pk0) * 8)];
                bf16x8 a1 = *(const bf16x8*)&Ps[pr1 * 32 + ((quad ^ pk1) * 8)];
                __builtin_amdgcn_s_setprio(1);
#pragma unroll
                for (int nj = 0; nj < 8; nj++) {
                    bf16x8 bfr = *(const bf16x8*)&Vs[cur][(nj * 16 + l15) * 64 +
                                                          (((hh * 4 + quad) ^ sw) * 8)];
                    o[0][nj] = __builtin_amdgcn_mfma_f32_16x16x32_bf16(a0, bfr, o[0][nj], 0, 0, 0);
                    o[1][nj] = __builtin_amdgcn_mfma_f32_16x16x32_bf16(a1, bfr, o[1][nj], 0, 0, 0);
                }
                __builtin_amdgcn_s_setprio(0);
            }
        }
        barx();   // all reads of buf[cur] done before next iter restages it
    }
#undef STAGE_KV

    // --- epilogue: reduce rowsum across l15 lanes, O/l * gate -> Og ---
    const int b_ = bh >> 4, h = bh & 15;
#pragma unroll
    for (int mi = 0; mi < 2; mi++)
#pragma unroll
        for (int i = 0; i < 4; i++) {
            float t = rowsum[mi][i];
#pragma unroll
            for (int off = 1; off < 16; off <<= 1) t += __shfl_xor(t, off, 16);
            float rl = 1.f / t;
            int l_ = qrow0 + mi * 16 + quad * 4 + i;
#pragma unroll
            for (int nj = 0; nj < 8; nj++) {
                int d = nj * 16 + l15;
                size_t gi = ((size_t)(b_ * 2048 + l_) * 2048) + h * 128 + d;
                Og[gi] = f2bf(o[mi][nj][i] * rl * bf2f(G[gi]));
            }
        }
}

// ---------------------------------------------------------------------------
// launch
// ---------------------------------------------------------------------------
extern "C" void kernel_launch(void* const* d_in, const int* in_sizes, int n_in,
                              void* d_out, int out_size, void* d_ws, size_t ws_size,
                              hipStream_t stream) {
    const float* X  = (const float*)d_in[0];   // (4,2048,2048)
    const float* Wq = (const float*)d_in[1];   // (2048,8192)
    const float* Wo = (const float*)d_in[2];   // (2048,2048)
    float* out = (float*)d_out;                // (4,2048,2048) fp32

    char* ws = (char*)d_ws;
    const size_t SZ = 33554432ull;             // 16.8M bf16
    unsigned short* Xb  = (unsigned short*)(ws);                 // X bf16 / later OG
    unsigned short* Wqt = (unsigned short*)(ws + SZ);            // Wqkvg^T
    unsigned short* Wot = (unsigned short*)(ws + 2 * SZ);        // 8.4 MB
    unsigned short* Qb  = (unsigned short*)(ws + 2 * SZ + 8388608ull);
    unsigned short* Kb  = (unsigned short*)(ws + 3 * SZ + 8388608ull);
    unsigned short* Vt  = (unsigned short*)(ws + 4 * SZ + 8388608ull);  // (bh,d,l)
    unsigned short* Gb  = (unsigned short*)(ws + 5 * SZ + 8388608ull);
    unsigned short* OG  = Xb;    // reuse: Xb dead after GEMM1

    cvt_bf16<<<16384, 256, 0, stream>>>(X, Xb);
    transpose_cvt<<<dim3(256, 64), dim3(32, 8), 0, stream>>>(Wq, Wqt, 2048, 8192);
    transpose_cvt<<<dim3(64, 64),  dim3(32, 8), 0, stream>>>(Wo, Wot, 2048, 2048);

    gemm_qkvg<<<dim3(32, 32), 512, 0, stream>>>(Xb, Wqt, Qb, Kb, Vt, Gb);

    rmsnorm_rope<<<dim3(8192, 2), 256, 0, stream>>>(Qb, Kb);

    fa_kernel<<<512, 512, 0, stream>>>(Qb, Kb, Vt, Gb, OG);

    gemm_out<<<dim3(8, 32), 512, 0, stream>>>(OG, Wot, out);
}

// Round 6
// 664.525 us; speedup vs baseline: 1.4373x; 1.4373x over previous
//
#include <hip/hip_runtime.h>

// ---------------------------------------------------------------------------
// Fused attention block, bf16 MFMA pipeline.
// B=4, L=2048, HID=2048, H=16, DH=128, QKV=6144.
// R11: (1) gemm core reverted to R8-exact — R9/R10's phase-ahead frag
// double-buffer spilled (VGPR ceiling: 128 AGPR acc + 128 arch = 256/wave
// at 2 waves/SIMD; WRITE_SIZE 132->178 MB scratch, dur 299->512 us).
// (2) fa block mapping: complementary (qc, 7-qc) chunks of the SAME head
// paired on one CU (g and g+256 co-resident under round-robin) — old
// mapping paired EQUAL qc: worst CU did 64 tiles vs mean 36 (makespan
// ~1.8x mean). New: every CU pair = exactly 36 tiles + shared K/V in L2.
// Keeps: R8 rmsnorm bf16x8 vectorization, fa K/V dbuf + vmcnt(4) + setprio.
// ---------------------------------------------------------------------------

typedef __attribute__((ext_vector_type(8))) short bf16x8;   // 8 bf16 = 4 VGPRs
typedef __attribute__((ext_vector_type(4))) float f32x4;
typedef __attribute__((ext_vector_type(4))) unsigned short us4;

#if __has_builtin(__builtin_amdgcn_exp2f)
#define EXP2(x) __builtin_amdgcn_exp2f(x)
#else
#define EXP2(x) exp2f(x)
#endif

__device__ __forceinline__ unsigned short f2bf(float f) {
    unsigned int x = __float_as_uint(f);
    unsigned int r = x + 0x7fffu + ((x >> 16) & 1u);   // RN-even
    return (unsigned short)(r >> 16);
}
__device__ __forceinline__ unsigned short f2bf_fast(float f) {   // round-half-up
    return (unsigned short)((__float_as_uint(f) + 0x8000u) >> 16);
}
__device__ __forceinline__ float bf2f(unsigned short u) {
    return __uint_as_float(((unsigned int)u) << 16);
}

// async global->LDS, 16 B per lane; LDS dest = wave-uniform base + lane*16
__device__ __forceinline__ void gll16(const unsigned short* g, unsigned short* l) {
    __builtin_amdgcn_global_load_lds(
        (const __attribute__((address_space(1))) unsigned int*)g,
        (__attribute__((address_space(3))) unsigned int*)l, 16, 0, 0);
}

// raw barrier with compiler memory fence (no vmcnt(0) drain like __syncthreads)
__device__ __forceinline__ void barx() {
    asm volatile("" ::: "memory");
    __builtin_amdgcn_s_barrier();
    asm volatile("" ::: "memory");
}
#define LGKM0() asm volatile("s_waitcnt lgkmcnt(0)" ::: "memory")
#define VM6()   asm volatile("s_waitcnt vmcnt(6)" ::: "memory")
#define VM4()   asm volatile("s_waitcnt vmcnt(4)" ::: "memory")
#define VM0()   asm volatile("s_waitcnt vmcnt(0)" ::: "memory")

// ---------------------------------------------------------------------------
// elementwise fp32 -> bf16 (vectorized float4 -> ushort4)
// ---------------------------------------------------------------------------
__global__ __launch_bounds__(256) void cvt_bf16(const float* __restrict__ in,
                                                unsigned short* __restrict__ out) {
    int i = blockIdx.x * 256 + threadIdx.x;       // over n/4
    float4 v = ((const float4*)in)[i];
    us4 r;
    r[0] = f2bf(v.x); r[1] = f2bf(v.y); r[2] = f2bf(v.z); r[3] = f2bf(v.w);
    ((us4*)out)[i] = r;
}

// ---------------------------------------------------------------------------
// fp32 (R x C) -> bf16 transposed (C x R).  block (32,8), 32x32 LDS tile.
// ---------------------------------------------------------------------------
__global__ __launch_bounds__(256) void transpose_cvt(const float* __restrict__ in,
                                                     unsigned short* __restrict__ out,
                                                     int R, int C) {
    __shared__ float t[32][33];
    int c0 = blockIdx.x * 32, r0 = blockIdx.y * 32;
    int tx = threadIdx.x, ty = threadIdx.y;
#pragma unroll
    for (int i = 0; i < 4; i++)
        t[ty + i * 8][tx] = in[(size_t)(r0 + ty + i * 8) * C + c0 + tx];
    __syncthreads();
#pragma unroll
    for (int i = 0; i < 4; i++)
        out[(size_t)(c0 + ty + i * 8) * R + r0 + tx] = f2bf(t[tx][ty + i * 8]);
}

// ---------------------------------------------------------------------------
// 256x256 8-phase GEMM core (R8-exact, ledger: 274-299 us on gemm_qkvg).
// C[256m x 256n] += A(M,K) * Bt(N,K)^T, bf16, BK=64. 512 thr = 8 waves
// (wm=w>>2, wn=w&3); wave output 128x64 = acc[8][4] 16x16x32 frags.
// LDS: sm[2 buf][2 mat][2 half][128*64] = 128 KiB, chunk-XOR swizzle (row&7).
// Schedule per K-tile t (4 phases, 2 barriers each):
//   p0: rd B(all 8)+A(q0) | stage (t+1) A-h1      | bar,lgkm0,prio,16 MFMA,bar
//   p1: rd A(q1)          | stage (t+2) B-h0      | ...
//   p2: rd A(q2)          | stage (t+2) B-h1      | ...
//   p3: rd A(q3)          | stage (t+2) A-h0, VM6 | ...
// vmcnt(6) drain math: 14 outstanding -> drains exactly all 4 slabs of t+1.
// NOTE (R10 lesson): do NOT double-buffer frag registers here — acc=128 AGPR
// + 128 arch VGPR is the full 2-wave/SIMD budget; extra frag state spills.
// ---------------------------------------------------------------------------
__device__ __forceinline__ void gemm256_core(const unsigned short* __restrict__ A,
                                             const unsigned short* __restrict__ Bt,
                                             int K, int rowA0, int colB0,
                                             unsigned short* sm,
                                             f32x4 acc[8][4]) {
    const int tid = threadIdx.x;
    const int w = tid >> 6, lane = tid & 63;
    const int quad = lane >> 4, l15 = lane & 15;
    const int wm = w >> 2, wn = w & 3;
    const int lr = lane >> 3;                 // row within the 8-row gll stripe
    const int lc = ((lane & 7) ^ lr) * 8;     // pre-swizzled source col within 64
    const int NT = K >> 6;

    const unsigned short* pA = A  + (size_t)(rowA0 + w * 16 + lr) * K + lc;
    const unsigned short* pB = Bt + (size_t)(colB0 + w * 16 + lr) * K + lc;
    unsigned short* lw = sm + w * 16 * 64;    // wave's stripe within any slab

#define STAGE(tt, isB, h)                                                       \
    do {                                                                        \
        const unsigned short* gp_ = ((isB) ? pB : pA) +                         \
            (size_t)(h) * 128 * K + (size_t)(tt) * 64;                          \
        unsigned short* lp_ = lw + (((tt) & 1) * 4 + (isB) * 2 + (h)) * 8192;   \
        gll16(gp_, lp_);                                                        \
        gll16(gp_ + (size_t)8 * K, lp_ + 8 * 64);                               \
    } while (0)

    // prologue: tile0 [B0,B1,A0,A1], tile1 [B0,B1,A0]; 14 loads in flight,
    // vmcnt(6) -> tile0 fully landed, tile1's 3 slabs remain in flight.
    STAGE(0, 1, 0); STAGE(0, 1, 1); STAGE(0, 0, 0); STAGE(0, 0, 1);
    STAGE(1, 1, 0); STAGE(1, 1, 1); STAGE(1, 0, 0);
    VM6();
    barx();

    for (int t = 0; t < NT; ++t) {
        const unsigned short* Asl = sm + ((t & 1) * 4 + wm) * 8192;
        const unsigned short* Bsl = sm + ((t & 1) * 4 + 2 + (wn >> 1)) * 8192;
        bf16x8 bfrag[4][2];
#pragma unroll
        for (int q = 0; q < 4; ++q) {
            if (q == 0) {
#pragma unroll
                for (int nj = 0; nj < 4; ++nj)
#pragma unroll
                    for (int kk = 0; kk < 2; ++kk) {
                        int r = (wn & 1) * 64 + nj * 16 + l15;
                        bfrag[nj][kk] = *(const bf16x8*)&Bsl[r * 64 +
                            (((kk * 4 + quad) ^ (r & 7)) * 8)];
                    }
            }
            bf16x8 afr[2][2];
#pragma unroll
            for (int mi = 0; mi < 2; ++mi)
#pragma unroll
                for (int kk = 0; kk < 2; ++kk) {
                    int r = q * 32 + mi * 16 + l15;
                    afr[mi][kk] = *(const bf16x8*)&Asl[r * 64 +
                        (((kk * 4 + quad) ^ (r & 7)) * 8)];
                }
            if (q == 0)      { if (t + 1 < NT) STAGE(t + 1, 0, 1); }
            else if (q == 1) { if (t + 2 < NT) STAGE(t + 2, 1, 0); }
            else if (q == 2) { if (t + 2 < NT) STAGE(t + 2, 1, 1); }
            else {
                if (t + 2 < NT)      { STAGE(t + 2, 0, 0); VM6(); }
                else if (t + 1 < NT) { VM0(); }      // tail drain (t = NT-2)
            }
            barx();
            LGKM0();
            __builtin_amdgcn_s_setprio(1);
#pragma unroll
            for (int mi = 0; mi < 2; ++mi)
#pragma unroll
                for (int nj = 0; nj < 4; ++nj)
#pragma unroll
                    for (int kk = 0; kk < 2; ++kk)
                        acc[q * 2 + mi][nj] = __builtin_amdgcn_mfma_f32_16x16x32_bf16(
                            afr[mi][kk], bfrag[nj][kk], acc[q * 2 + mi][nj], 0, 0, 0);
            __builtin_amdgcn_s_setprio(0);
            barx();
        }
    }
#undef STAGE
}

// ---------------------------------------------------------------------------
// GEMM1: proj = Xb @ Wqkvg.  256-col tile = 2 heads of one section.
// Epilogue: q/k scatter -> (b,h,l,d); V written TRANSPOSED -> Vt (b,h,d,l)
// via 128 KiB LDS reuse (fused transpose_v); gate -> sigmoid.
// Mapping (R6-proven): per-XCD 4 by-rows x all 32 bx — A-slab L2-resident,
// B streamed via LLC.
// ---------------------------------------------------------------------------
__global__ __launch_bounds__(512) void gemm_qkvg(const unsigned short* __restrict__ A,
                                                 const unsigned short* __restrict__ Bt,
                                                 unsigned short* __restrict__ Qb,
                                                 unsigned short* __restrict__ Kb,
                                                 unsigned short* __restrict__ Vt,
                                                 unsigned short* __restrict__ Gb) {
    __shared__ unsigned short sm[8 * 8192];    // 128 KiB
    f32x4 acc[8][4];
    f32x4 z = {0.f, 0.f, 0.f, 0.f};
#pragma unroll
    for (int i = 0; i < 8; i++)
#pragma unroll
        for (int j = 0; j < 4; j++) acc[i][j] = z;

    // XCD-chunked bijective swizzle (1024 wgs, 1024 % 8 == 0)
    const int g = blockIdx.y * 32 + blockIdx.x;
    const int gs = (g & 7) * 128 + (g >> 3);
    const int bx = gs & 31, by = gs >> 5;
    const int rowA0 = by * 256, colB0 = bx * 256;
    gemm256_core(A, Bt, 2048, rowA0, colB0, sm, acc);

    const int tid = threadIdx.x, w = tid >> 6, lane = tid & 63;
    const int quad = lane >> 4, l15 = lane & 15;
    const int wm = w >> 2, wn = w & 3;
    const int sec = colB0 >> 11;              // 0=q 1=k 2=v 3=gate
    const int hbase = (colB0 & 2047) >> 7;    // even head base within section

    if (sec == 2) {
        // V: acc -> LDS as two (d, l) 128x256 head-tiles, 16B-chunk swizzled
        // (chunk ^= d&31); core's final barrier means all LDS reads are done.
#pragma unroll
        for (int mi = 0; mi < 8; ++mi)
#pragma unroll
            for (int nj = 0; nj < 4; ++nj)
#pragma unroll
                for (int i = 0; i < 4; ++i) {
                    int ll = wm * 128 + mi * 16 + quad * 4 + i;   // l in tile
                    int c  = wn * 64 + nj * 16 + l15;             // 0..255
                    int hh = c >> 7, d = c & 127;
                    sm[hh * 32768 + d * 256 + (((ll >> 3) ^ (d & 31)) * 8) + (ll & 7)] =
                        f2bf(acc[mi][nj][i]);
                }
        __syncthreads();
        const int b_ = rowA0 >> 11, l0 = rowA0 & 2047;
        const int d = tid >> 2, part = tid & 3;    // d row, 64-col quarter
#pragma unroll
        for (int hh = 0; hh < 2; ++hh) {
            unsigned short* drow = Vt +
                ((size_t)(b_ * 16 + hbase + hh) * 128 + d) * 2048 + l0 + part * 64;
#pragma unroll
            for (int j = 0; j < 8; ++j) {
                int chunk = part * 8 + j;
                *(bf16x8*)(drow + j * 8) =
                    *(const bf16x8*)&sm[hh * 32768 + d * 256 + ((chunk ^ (d & 31)) * 8)];
            }
        }
    } else if (sec == 3) {
#pragma unroll
        for (int mi = 0; mi < 8; ++mi)
#pragma unroll
            for (int nj = 0; nj < 4; ++nj)
#pragma unroll
                for (int i = 0; i < 4; ++i) {
                    int rowg = rowA0 + wm * 128 + mi * 16 + quad * 4 + i;  // b*L+l
                    int c = wn * 64 + nj * 16 + l15;
                    int h = hbase + (c >> 7), d = c & 127;
                    float gv = 1.f / (1.f + __expf(-acc[mi][nj][i]));
                    Gb[((size_t)rowg << 11) + h * 128 + d] = f2bf(gv);
                }
    } else {
        unsigned short* dst = (sec == 0) ? Qb : Kb;
#pragma unroll
        for (int mi = 0; mi < 8; ++mi)
#pragma unroll
            for (int nj = 0; nj < 4; ++nj)
#pragma unroll
                for (int i = 0; i < 4; ++i) {
                    int rowg = rowA0 + wm * 128 + mi * 16 + quad * 4 + i;
                    int c = wn * 64 + nj * 16 + l15;
                    int h = hbase + (c >> 7), d = c & 127;
                    int b_ = rowg >> 11, l_ = rowg & 2047;
                    dst[(((size_t)(b_ * 16 + h) * 2048 + l_) << 7) + d] =
                        f2bf(acc[mi][nj][i]);
                }
    }
}

// ---------------------------------------------------------------------------
// GEMM2: out = OG @ Wout  (fp32 epilogue straight to d_out)
// ---------------------------------------------------------------------------
__global__ __launch_bounds__(512) void gemm_out(const unsigned short* __restrict__ A,
                                                const unsigned short* __restrict__ Bt,
                                                float* __restrict__ C) {
    __shared__ unsigned short sm[8 * 8192];    // 128 KiB
    f32x4 acc[8][4];
    f32x4 z = {0.f, 0.f, 0.f, 0.f};
#pragma unroll
    for (int i = 0; i < 8; i++)
#pragma unroll
        for (int j = 0; j < 4; j++) acc[i][j] = z;

    const int g = blockIdx.y * 8 + blockIdx.x;      // 256 wgs, 256 % 8 == 0
    const int gs = (g & 7) * 32 + (g >> 3);
    const int bx = gs & 7, by = gs >> 3;
    const int rowA0 = by * 256, colB0 = bx * 256;
    gemm256_core(A, Bt, 2048, rowA0, colB0, sm, acc);

    const int tid = threadIdx.x, w = tid >> 6, lane = tid & 63;
    const int quad = lane >> 4, l15 = lane & 15;
    const int wm = w >> 2, wn = w & 3;
#pragma unroll
    for (int mi = 0; mi < 8; ++mi)
#pragma unroll
        for (int nj = 0; nj < 4; ++nj)
#pragma unroll
            for (int i = 0; i < 4; ++i) {
                int rowg = rowA0 + wm * 128 + mi * 16 + quad * 4 + i;
                int col = colB0 + wn * 64 + nj * 16 + l15;
                C[(size_t)rowg * 2048 + col] = acc[mi][nj][i];
            }
}

// ---------------------------------------------------------------------------
// RMSNorm + RoPE in place on Q and K (each (64, 2048, 128) bf16), one launch.
// Vectorized — 16 lanes per row, bf16x8 (16B) loads/stores. Lane l16 owns
// elements [sub*64 + l8*8, +8); SS reduced over the 16-lane group; rotate-
// half partner via shfl_xor(8,16). 4 rows/wave, 16 rows/block.
// ---------------------------------------------------------------------------
__global__ __launch_bounds__(256) void rmsnorm_rope(unsigned short* __restrict__ Qp,
                                                    unsigned short* __restrict__ Kp) {
    unsigned short* X = blockIdx.y ? Kp : Qp;
    const int tid = threadIdx.x;
    const int wv = tid >> 6, lane = tid & 63;
    const int rgrp = lane >> 4;                 // row within wave: 0..3
    const int l16 = lane & 15;
    const int sub = l16 >> 3, l8 = l16 & 7;     // half, 8-elem chunk
    const int row = blockIdx.x * 16 + wv * 4 + rgrp;
    unsigned short* p = X + (size_t)row * 128 + sub * 64 + l8 * 8;
    const int pos = row & 2047;                 // sequence position

    bf16x8 v = *(const bf16x8*)p;
    float x[8];
    float ss = 0.f;
#pragma unroll
    for (int j = 0; j < 8; j++) {
        x[j] = bf2f((unsigned short)v[j]);
        ss += x[j] * x[j];
    }
#pragma unroll
    for (int off = 8; off >= 1; off >>= 1) ss += __shfl_xor(ss, off, 16);
    const float r = rsqrtf(ss * (1.f / 128.f) + 1e-5f);

    float xs[8], xp[8];
#pragma unroll
    for (int j = 0; j < 8; j++) xs[j] = x[j] * r;
#pragma unroll
    for (int j = 0; j < 8; j++) xp[j] = __shfl_xor(xs[j], 8, 16);  // other half

    const float sgn = sub ? 1.f : -1.f;     // out = xs*cos + xp*(sub? sin:-sin)
    bf16x8 o;
#pragma unroll
    for (int j = 0; j < 8; j++) {
        int k = l8 * 8 + j;                  // frequency index 0..63
        float inv = exp2f(-(float)k * (13.287712379549449f / 64.f));
        float ang = (float)pos * inv;
        float sn, cs;
        sincosf(ang, &sn, &cs);
        o[j] = (short)f2bf(xs[j] * cs + xp[j] * (sgn * sn));
    }
    *(bf16x8*)p = o;
}

// ---------------------------------------------------------------------------
// Flash attention (causal) + gate fusion, no-max softmax.
// grid 512 blocks, 512 threads = 8 waves; q-tile 256 (wave w owns q rows
// [w*32, w*32+32)); KV tile 64, PV in two 32-kv halves so Ps is 16 KB.
// K/V double-buffered (LDS 80 KB), tile j+1 prefetched during tile j
// compute, counted vmcnt(4); setprio around MFMA clusters (T5).
// R11 mapping: g = x + 256*h -> bh = (x&7)|((x>>5)<<3), qq = (x>>3)&3,
// qc = h ? qq : 7-qq.  Blocks g and g+256 (same x) co-resident on one CU
// under round-robin assignment: complementary work (4(8-qq)+4(qq+1) = 36
// tiles on EVERY CU pair) + both blocks stream the same head's K/V (L2).
// All 4 x-variants of a head and both halves are ≡ x (mod 8): one XCD/head.
// P is wave-local: no barrier between P write and PV read.
// ---------------------------------------------------------------------------
__global__ __launch_bounds__(512) void fa_kernel(const unsigned short* __restrict__ Q,
                                                 const unsigned short* __restrict__ K,
                                                 const unsigned short* __restrict__ Vt,
                                                 const unsigned short* __restrict__ G,
                                                 unsigned short* __restrict__ Og) {
    __shared__ unsigned short Ks[2][64 * 128];  // (kv, d) double-buffered
    __shared__ unsigned short Vs[2][128 * 64];  // (d, kv) double-buffered
    __shared__ unsigned short Ps[256 * 32];     // (q, kv-half) wave-local slabs
    const int g = blockIdx.x;
    const int x = g & 255, hf_ = g >> 8;        // pair id, half
    const int bh = (x & 7) | ((x >> 5) << 3);   // batch*16 + head
    const int qq = (x >> 3) & 3;
    const int qc = hf_ ? qq : 7 - qq;           // complementary pairs per CU
    const int tid = threadIdx.x, w = tid >> 6, lane = tid & 63;
    const int quad = lane >> 4, l15 = lane & 15;
    const int sw = l15 & 7;
    const int qrow0 = qc * 256 + w * 32;        // global q row base for this wave
    const float CS = 0.12751740395609812f;      // (1/sqrt(128)) * log2(e)

    // Q fragments (A-operand layout), loaded once
    bf16x8 qf[2][4];
#pragma unroll
    for (int mi = 0; mi < 2; mi++)
#pragma unroll
        for (int kt = 0; kt < 4; kt++)
            qf[mi][kt] = *(const bf16x8*)(Q + ((size_t)bh * 2048 + qrow0 + mi * 16 + l15) * 128
                                             + kt * 32 + quad * 8);

    f32x4 o[2][8];
    f32x4 z = {0.f, 0.f, 0.f, 0.f};
#pragma unroll
    for (int mi = 0; mi < 2; mi++)
#pragma unroll
        for (int nj = 0; nj < 8; nj++) o[mi][nj] = z;
    float rowsum[2][4];
#pragma unroll
    for (int mi = 0; mi < 2; mi++)
#pragma unroll
        for (int i = 0; i < 4; i++) rowsum[mi][i] = 0.f;

    const unsigned short* Kbase = K + (size_t)bh * 2048 * 128;
    const unsigned short* Vtb   = Vt + (size_t)bh * 128 * 2048;

    // staging lane decomposition (4 gll16 per wave per tile)
    const int krow = lane >> 4, kc = lane & 15;   // K: 4 rows x 16 chunks
    const int vrow = lane >> 3, vc = lane & 7;    // V: 8 rows x 8 chunks

#define STAGE_KV(jj, buf)                                                        \
    do {                                                                         \
        _Pragma("unroll")                                                        \
        for (int i_ = 0; i_ < 2; i_++) {                                         \
            int r0_ = w * 8 + i_ * 4;                                            \
            int row_ = r0_ + krow;                                               \
            int cs_ = (kc & 8) | ((kc & 7) ^ (row_ & 7));                        \
            gll16(Kbase + (size_t)((jj) * 64 + row_) * 128 + cs_ * 8,            \
                  &Ks[buf][r0_ * 128]);                                          \
        }                                                                        \
        _Pragma("unroll")                                                        \
        for (int i_ = 0; i_ < 2; i_++) {                                         \
            int r0_ = w * 16 + i_ * 8;                                           \
            int row_ = r0_ + vrow;                                               \
            gll16(Vtb + (size_t)row_ * 2048 + (jj) * 64 + ((vc ^ (row_ & 7)) * 8), \
                  &Vs[buf][r0_ * 64]);                                           \
        }                                                                        \
    } while (0)

    // Ps a-frag read offsets (row-dependent swizzle key = (row>>1)&3)
    const int pr0 = w * 32 + l15, pr1 = pr0 + 16;
    const int pk0 = (pr0 >> 1) & 3, pk1 = (pr1 >> 1) & 3;

    const int NJ = 4 * (qc + 1);    // kv tiles of 64

    STAGE_KV(0, 0);                 // prologue: tile 0 in flight

    for (int j = 0; j < NJ; j++) {
        const int cur = j & 1;
        // prefetch tile j+1 into the other buffer; its 4 loads ride across
        // this tile's compute. vmcnt(4) waits only for tile j's 4 loads.
        if (j + 1 < NJ) { STAGE_KV(j + 1, cur ^ 1); VM4(); }
        else            { VM0(); }
        barx();   // tile j staged + all waves' prior-tile reads done

        if (j * 64 < qrow0 + 32) {
            // --- S = Q K^T (raw logits) ---
            f32x4 s[2][4];
#pragma unroll
            for (int mi = 0; mi < 2; mi++)
#pragma unroll
                for (int nj = 0; nj < 4; nj++) s[mi][nj] = z;
            __builtin_amdgcn_s_setprio(1);
#pragma unroll
            for (int kt = 0; kt < 4; kt++)
#pragma unroll
                for (int nj = 0; nj < 4; nj++) {
                    bf16x8 bfr = *(const bf16x8*)&Ks[cur][(nj * 16 + l15) * 128 +
                                                         (((kt * 4 + quad) ^ sw) * 8)];
                    s[0][nj] = __builtin_amdgcn_mfma_f32_16x16x32_bf16(qf[0][kt], bfr, s[0][nj], 0, 0, 0);
                    s[1][nj] = __builtin_amdgcn_mfma_f32_16x16x32_bf16(qf[1][kt], bfr, s[1][nj], 0, 0, 0);
                }
            __builtin_amdgcn_s_setprio(0);

            // --- two 32-kv halves: exp + P write + PV MFMA (Ps wave-local) ---
            const bool diag = (j * 64 + 63 > qrow0);   // any masking in this tile?
#pragma unroll
            for (int hh = 0; hh < 2; hh++) {
#pragma unroll
                for (int mi = 0; mi < 2; mi++)
#pragma unroll
                    for (int njh = 0; njh < 2; njh++) {
                        const int nj = hh * 2 + njh;
#pragma unroll
                        for (int i = 0; i < 4; i++) {
                            float pp = EXP2(s[mi][nj][i] * CS);
                            int row_l = mi * 16 + quad * 4 + i;      // 0..31 in slab
                            if (diag) {
                                int col_g = j * 64 + nj * 16 + l15;
                                if (col_g > qrow0 + row_l) pp = 0.f;
                            }
                            rowsum[mi][i] += pp;
                            int row = w * 32 + row_l;
                            int kv = njh * 16 + l15;                 // 0..31
                            Ps[row * 32 + ((((kv >> 3) ^ ((row >> 1) & 3)) * 8)) + (kv & 7)] =
                                f2bf_fast(pp);
                        }
                    }
                // PV for this half (K=32 -> one MFMA pair per o-column)
                bf16x8 a0 = *(const bf16x8*)&Ps[pr0 * 32 + ((quad ^ pk0) * 8)];
                bf16x8 a1 = *(const bf16x8*)&Ps[pr1 * 32 + ((quad ^ pk1) * 8)];
                __builtin_amdgcn_s_setprio(1);
#pragma unroll
                for (int nj = 0; nj < 8; nj++) {
                    bf16x8 bfr = *(const bf16x8*)&Vs[cur][(nj * 16 + l15) * 64 +
                                                          (((hh * 4 + quad) ^ sw) * 8)];
                    o[0][nj] = __builtin_amdgcn_mfma_f32_16x16x32_bf16(a0, bfr, o[0][nj], 0, 0, 0);
                    o[1][nj] = __builtin_amdgcn_mfma_f32_16x16x32_bf16(a1, bfr, o[1][nj], 0, 0, 0);
                }
                __builtin_amdgcn_s_setprio(0);
            }
        }
        barx();   // all reads of buf[cur] done before next iter restages it
    }
#undef STAGE_KV

    // --- epilogue: reduce rowsum across l15 lanes, O/l * gate -> Og ---
    const int b_ = bh >> 4, h = bh & 15;
#pragma unroll
    for (int mi = 0; mi < 2; mi++)
#pragma unroll
        for (int i = 0; i < 4; i++) {
            float t = rowsum[mi][i];
#pragma unroll
            for (int off = 1; off < 16; off <<= 1) t += __shfl_xor(t, off, 16);
            float rl = 1.f / t;
            int l_ = qrow0 + mi * 16 + quad * 4 + i;
#pragma unroll
            for (int nj = 0; nj < 8; nj++) {
                int d = nj * 16 + l15;
                size_t gi = ((size_t)(b_ * 2048 + l_) * 2048) + h * 128 + d;
                Og[gi] = f2bf(o[mi][nj][i] * rl * bf2f(G[gi]));
            }
        }
}

// ---------------------------------------------------------------------------
// launch
// ---------------------------------------------------------------------------
extern "C" void kernel_launch(void* const* d_in, const int* in_sizes, int n_in,
                              void* d_out, int out_size, void* d_ws, size_t ws_size,
                              hipStream_t stream) {
    const float* X  = (const float*)d_in[0];   // (4,2048,2048)
    const float* Wq = (const float*)d_in[1];   // (2048,8192)
    const float* Wo = (const float*)d_in[2];   // (2048,2048)
    float* out = (float*)d_out;                // (4,2048,2048) fp32

    char* ws = (char*)d_ws;
    const size_t SZ = 33554432ull;             // 16.8M bf16
    unsigned short* Xb  = (unsigned short*)(ws);                 // X bf16 / later OG
    unsigned short* Wqt = (unsigned short*)(ws + SZ);            // Wqkvg^T
    unsigned short* Wot = (unsigned short*)(ws + 2 * SZ);        // 8.4 MB
    unsigned short* Qb  = (unsigned short*)(ws + 2 * SZ + 8388608ull);
    unsigned short* Kb  = (unsigned short*)(ws + 3 * SZ + 8388608ull);
    unsigned short* Vt  = (unsigned short*)(ws + 4 * SZ + 8388608ull);  // (bh,d,l)
    unsigned short* Gb  = (unsigned short*)(ws + 5 * SZ + 8388608ull);
    unsigned short* OG  = Xb;    // reuse: Xb dead after GEMM1

    cvt_bf16<<<16384, 256, 0, stream>>>(X, Xb);
    transpose_cvt<<<dim3(256, 64), dim3(32, 8), 0, stream>>>(Wq, Wqt, 2048, 8192);
    transpose_cvt<<<dim3(64, 64),  dim3(32, 8), 0, stream>>>(Wo, Wot, 2048, 2048);

    gemm_qkvg<<<dim3(32, 32), 512, 0, stream>>>(Xb, Wqt, Qb, Kb, Vt, Gb);

    rmsnorm_rope<<<dim3(8192, 2), 256, 0, stream>>>(Qb, Kb);

    fa_kernel<<<512, 512, 0, stream>>>(Qb, Kb, Vt, Gb, OG);

    gemm_out<<<dim3(8, 32), 512, 0, stream>>>(OG, Wot, out);
}